// Round 1
// baseline (2781.215 us; speedup 1.0000x reference)
//
#include <hip/hip_runtime.h>

#define N_NODES 100000
#define N_FEAT  128
#define N_EDGES 1600000

// Phase 1: deg[i] = 1.0 (self-loop weight)
__global__ void k_init_deg(float* __restrict__ deg) {
    int i = blockIdx.x * blockDim.x + threadIdx.x;
    if (i < N_NODES) deg[i] = 1.0f;
}

// Phase 2: deg[src[e]] += w[e]
__global__ void k_accum_deg(const int* __restrict__ src,
                            const float* __restrict__ w,
                            float* __restrict__ deg) {
    int e = blockIdx.x * blockDim.x + threadIdx.x;
    if (e < N_EDGES) atomicAdd(&deg[src[e]], w[e]);
}

// Phase 3a: deg[i] = 1 / max(deg[i], 1)
__global__ void k_inv_deg(float* __restrict__ deg) {
    int i = blockIdx.x * blockDim.x + threadIdx.x;
    if (i < N_NODES) deg[i] = 1.0f / fmaxf(deg[i], 1.0f);
}

// Phase 3b: out = x * inv_deg  (self-loop term; fully initializes d_out)
__global__ void k_self(const float4* __restrict__ x4,
                       const float* __restrict__ inv,
                       float4* __restrict__ out4) {
    int idx = blockIdx.x * blockDim.x + threadIdx.x;   // over N*F/4
    if (idx < N_NODES * (N_FEAT / 4)) {
        int node = idx >> 5;                            // 32 float4 per node
        float s = inv[node];
        float4 v = x4[idx];
        out4[idx] = make_float4(v.x * s, v.y * s, v.z * s, v.w * s);
    }
}

// Phase 4: per-edge scatter. 32 lanes per edge, each lane: float4 of x[dst],
// 4 atomicAdds into out[src].
__global__ void k_edges(const int* __restrict__ src,
                        const int* __restrict__ dst,
                        const float* __restrict__ w,
                        const float* __restrict__ inv,
                        const float4* __restrict__ x4,
                        float* __restrict__ out) {
    long long gid = (long long)blockIdx.x * blockDim.x + threadIdx.x;
    int e    = (int)(gid >> 5);
    int lane = (int)(gid & 31);
    if (e < N_EDGES) {
        int s = src[e];
        int d = dst[e];
        float sc = w[e] * inv[s];
        float4 v = x4[(long long)d * (N_FEAT / 4) + lane];
        float* ob = out + (long long)s * N_FEAT + lane * 4;
        atomicAdd(ob + 0, sc * v.x);
        atomicAdd(ob + 1, sc * v.y);
        atomicAdd(ob + 2, sc * v.z);
        atomicAdd(ob + 3, sc * v.w);
    }
}

extern "C" void kernel_launch(void* const* d_in, const int* in_sizes, int n_in,
                              void* d_out, int out_size, void* d_ws, size_t ws_size,
                              hipStream_t stream) {
    const float* x          = (const float*)d_in[0];
    const int*   edge_index = (const int*)d_in[1];   // (2, E) row-major
    const float* edge_w     = (const float*)d_in[2];

    const int* src = edge_index;            // row 0
    const int* dst = edge_index + N_EDGES;  // row 1

    float* out = (float*)d_out;
    float* deg = (float*)d_ws;              // N_NODES floats, becomes inv_deg

    const int B = 256;

    k_init_deg<<<(N_NODES + B - 1) / B, B, 0, stream>>>(deg);
    k_accum_deg<<<(N_EDGES + B - 1) / B, B, 0, stream>>>(src, edge_w, deg);
    k_inv_deg<<<(N_NODES + B - 1) / B, B, 0, stream>>>(deg);

    int n4 = N_NODES * (N_FEAT / 4);
    k_self<<<(n4 + B - 1) / B, B, 0, stream>>>((const float4*)x, deg, (float4*)out);

    long long total = (long long)N_EDGES * 32;
    k_edges<<<(int)((total + B - 1) / B), B, 0, stream>>>(
        src, dst, edge_w, deg, (const float4*)x, out);
}

// Round 2
// 399.431 us; speedup vs baseline: 6.9629x; 6.9629x over previous
//
#include <hip/hip_runtime.h>

#define N_NODES 100000
#define N_FEAT  128
#define N_EDGES 1600000

// ---------- workspace layout ----------
constexpr size_t align_up(size_t x) { return (x + 255) & ~size_t(255); }
constexpr size_t OFF_CNT = 0;                                   // N ints
constexpr size_t OFF_ROW = OFF_CNT + align_up(N_NODES * 4);     // N ints
constexpr size_t OFF_CUR = OFF_ROW + align_up(N_NODES * 4);     // N ints
constexpr size_t OFF_DEG = OFF_CUR + align_up(N_NODES * 4);     // N floats -> inv_deg
constexpr size_t OFF_TOT = OFF_DEG + align_up(N_NODES * 4);     // 1 int
constexpr size_t OFF_DST = OFF_TOT + 256;                       // E ints
constexpr size_t OFF_W   = OFF_DST + align_up(N_EDGES * 4);     // E floats
constexpr size_t WS_NEED = OFF_W + N_EDGES * 4;                 // ~14.4 MB

// ---------- CSR build ----------
__global__ void k_init(int* __restrict__ cnt, float* __restrict__ deg,
                       int* __restrict__ total) {
    int i = blockIdx.x * blockDim.x + threadIdx.x;
    if (i < N_NODES) { cnt[i] = 0; deg[i] = 1.0f; }
    if (i == 0) *total = 0;
}

__global__ void k_count(const int* __restrict__ src, const float* __restrict__ w,
                        int* __restrict__ cnt, float* __restrict__ deg) {
    int e = blockIdx.x * blockDim.x + threadIdx.x;
    if (e < N_EDGES) {
        int s = src[e];
        atomicAdd(&cnt[s], 1);
        atomicAdd(&deg[s], w[e]);
    }
}

__global__ void k_alloc(const int* __restrict__ cnt, int* __restrict__ rowstart,
                        int* __restrict__ cursor, float* __restrict__ deg,
                        int* __restrict__ total) {
    int i = blockIdx.x * blockDim.x + threadIdx.x;
    if (i < N_NODES) {
        int c = cnt[i];
        int s = atomicAdd(total, c);
        rowstart[i] = s;
        cursor[i]   = s;
        deg[i] = 1.0f / fmaxf(deg[i], 1.0f);   // deg becomes inv_deg
    }
}

__global__ void k_scatter(const int* __restrict__ src, const int* __restrict__ dst,
                          const float* __restrict__ w, int* __restrict__ cursor,
                          int* __restrict__ csr_dst, float* __restrict__ csr_w) {
    int e = blockIdx.x * blockDim.x + threadIdx.x;
    if (e < N_EDGES) {
        int pos = atomicAdd(&cursor[src[e]], 1);
        csr_dst[pos] = dst[e];
        csr_w[pos]   = w[e];
    }
}

// ---------- aggregation: one 64-lane wave per node ----------
__global__ __launch_bounds__(256) void k_agg(
    const int* __restrict__ rowstart, const int* __restrict__ cnt,
    const float* __restrict__ inv,
    const int* __restrict__ csr_dst, const float* __restrict__ csr_w,
    const float2* __restrict__ x2, float2* __restrict__ out2) {
    int wid  = (int)((blockIdx.x * (long long)blockDim.x + threadIdx.x) >> 6);
    int lane = threadIdx.x & 63;
    if (wid >= N_NODES) return;

    int s = rowstart[wid];
    int c = cnt[wid];

    float2 acc = x2[(size_t)wid * 64 + lane];   // self-loop, weight 1

    for (int base = 0; base < c; base += 64) {
        int   dv = 0;
        float wv = 0.0f;
        int idx = base + lane;
        if (idx < c) { dv = csr_dst[s + idx]; wv = csr_w[s + idx]; }  // coalesced
        int m = min(64, c - base);
        int k = 0;
        // 2-wide to expose load-level parallelism
        for (; k + 1 < m; k += 2) {
            int   d0 = __shfl(dv, k),     d1 = __shfl(dv, k + 1);
            float w0 = __shfl(wv, k),     w1 = __shfl(wv, k + 1);
            float2 v0 = x2[(size_t)d0 * 64 + lane];
            float2 v1 = x2[(size_t)d1 * 64 + lane];
            acc.x += w0 * v0.x + w1 * v1.x;
            acc.y += w0 * v0.y + w1 * v1.y;
        }
        for (; k < m; ++k) {
            int   d = __shfl(dv, k);
            float w = __shfl(wv, k);
            float2 v = x2[(size_t)d * 64 + lane];
            acc.x += w * v.x;
            acc.y += w * v.y;
        }
    }
    float si = inv[wid];
    out2[(size_t)wid * 64 + lane] = make_float2(acc.x * si, acc.y * si);
}

// ---------- fallback (ws too small): round-1 atomic path ----------
__global__ void fb_init_deg(float* __restrict__ deg) {
    int i = blockIdx.x * blockDim.x + threadIdx.x;
    if (i < N_NODES) deg[i] = 1.0f;
}
__global__ void fb_accum_deg(const int* __restrict__ src, const float* __restrict__ w,
                             float* __restrict__ deg) {
    int e = blockIdx.x * blockDim.x + threadIdx.x;
    if (e < N_EDGES) atomicAdd(&deg[src[e]], w[e]);
}
__global__ void fb_inv_deg(float* __restrict__ deg) {
    int i = blockIdx.x * blockDim.x + threadIdx.x;
    if (i < N_NODES) deg[i] = 1.0f / fmaxf(deg[i], 1.0f);
}
__global__ void fb_self(const float4* __restrict__ x4, const float* __restrict__ inv,
                        float4* __restrict__ out4) {
    int idx = blockIdx.x * blockDim.x + threadIdx.x;
    if (idx < N_NODES * (N_FEAT / 4)) {
        int node = idx >> 5;
        float s = inv[node];
        float4 v = x4[idx];
        out4[idx] = make_float4(v.x * s, v.y * s, v.z * s, v.w * s);
    }
}
__global__ void fb_edges(const int* __restrict__ src, const int* __restrict__ dst,
                         const float* __restrict__ w, const float* __restrict__ inv,
                         const float4* __restrict__ x4, float* __restrict__ out) {
    long long gid = (long long)blockIdx.x * blockDim.x + threadIdx.x;
    int e = (int)(gid >> 5);
    int lane = (int)(gid & 31);
    if (e < N_EDGES) {
        int s = src[e];
        float sc = w[e] * inv[s];
        float4 v = x4[(long long)dst[e] * (N_FEAT / 4) + lane];
        float* ob = out + (long long)s * N_FEAT + lane * 4;
        atomicAdd(ob + 0, sc * v.x);
        atomicAdd(ob + 1, sc * v.y);
        atomicAdd(ob + 2, sc * v.z);
        atomicAdd(ob + 3, sc * v.w);
    }
}

extern "C" void kernel_launch(void* const* d_in, const int* in_sizes, int n_in,
                              void* d_out, int out_size, void* d_ws, size_t ws_size,
                              hipStream_t stream) {
    const float* x          = (const float*)d_in[0];
    const int*   edge_index = (const int*)d_in[1];   // (2, E) row-major
    const float* edge_w     = (const float*)d_in[2];
    const int* src = edge_index;
    const int* dst = edge_index + N_EDGES;
    float* out = (float*)d_out;

    const int B = 256;

    if (ws_size < WS_NEED) {
        // fallback: atomic scatter (round-1 path), needs only N floats of ws
        float* deg = (float*)d_ws;
        fb_init_deg<<<(N_NODES + B - 1) / B, B, 0, stream>>>(deg);
        fb_accum_deg<<<(N_EDGES + B - 1) / B, B, 0, stream>>>(src, edge_w, deg);
        fb_inv_deg<<<(N_NODES + B - 1) / B, B, 0, stream>>>(deg);
        int n4 = N_NODES * (N_FEAT / 4);
        fb_self<<<(n4 + B - 1) / B, B, 0, stream>>>((const float4*)x, deg, (float4*)out);
        long long total = (long long)N_EDGES * 32;
        fb_edges<<<(int)((total + B - 1) / B), B, 0, stream>>>(
            src, dst, edge_w, deg, (const float4*)x, out);
        return;
    }

    char* ws = (char*)d_ws;
    int*   cnt      = (int*)  (ws + OFF_CNT);
    int*   rowstart = (int*)  (ws + OFF_ROW);
    int*   cursor   = (int*)  (ws + OFF_CUR);
    float* deg      = (float*)(ws + OFF_DEG);
    int*   total    = (int*)  (ws + OFF_TOT);
    int*   csr_dst  = (int*)  (ws + OFF_DST);
    float* csr_w    = (float*)(ws + OFF_W);

    k_init<<<(N_NODES + B - 1) / B, B, 0, stream>>>(cnt, deg, total);
    k_count<<<(N_EDGES + B - 1) / B, B, 0, stream>>>(src, edge_w, cnt, deg);
    k_alloc<<<(N_NODES + B - 1) / B, B, 0, stream>>>(cnt, rowstart, cursor, deg, total);
    k_scatter<<<(N_EDGES + B - 1) / B, B, 0, stream>>>(src, dst, edge_w, cursor,
                                                       csr_dst, csr_w);

    long long threads = (long long)N_NODES * 64;
    k_agg<<<(int)((threads + B - 1) / B), B, 0, stream>>>(
        rowstart, cnt, deg, csr_dst, csr_w, (const float2*)x, (float2*)out);
}

// Round 3
// 244.962 us; speedup vs baseline: 11.3537x; 1.6306x over previous
//
#include <hip/hip_runtime.h>

#define N_NODES 100000
#define N_FEAT  128
#define N_EDGES 1600000
#define SLOTS   64
#define OVF_CAP 65536

constexpr size_t align_up(size_t x) { return (x + 255) & ~size_t(255); }

// ---- fast-path workspace layout ----
constexpr size_t OFF_CUR  = 0;                                    // N ints (zeroed)
constexpr size_t OFF_DEGX = OFF_CUR  + align_up(N_NODES * 4);     // N floats (zeroed)
constexpr size_t OFF_OVFC = OFF_DEGX + align_up(N_NODES * 4);     // 1 int (zeroed)
constexpr size_t OFF_INV  = OFF_OVFC + 256;                       // N floats
constexpr size_t OFF_OVF  = OFF_INV  + align_up(N_NODES * 4);     // OVF_CAP * 12 B
constexpr size_t OFF_SLOT = OFF_OVF  + align_up(OVF_CAP * 12);    // N*SLOTS uint2
constexpr size_t WS_FAST  = OFF_SLOT + (size_t)N_NODES * SLOTS * 8;  // ~53.2 MB
constexpr size_t ZERO_LEN = OFF_OVFC + 256;                       // memset range

// ---------------- fast path ----------------
__global__ void k_build(const int* __restrict__ src, const int* __restrict__ dst,
                        const float* __restrict__ w,
                        int* __restrict__ cursor, uint2* __restrict__ slots,
                        float* __restrict__ degx,
                        int* __restrict__ ovf_cnt, int* __restrict__ ovf) {
    int e = blockIdx.x * blockDim.x + threadIdx.x;
    if (e >= N_EDGES) return;
    int   s = src[e];
    int   d = dst[e];
    float ww = w[e];
    int c = atomicAdd(&cursor[s], 1);
    if (c < SLOTS) {
        uint2 v;
        v.x = (unsigned)d;
        v.y = __float_as_uint(ww);
        slots[(size_t)s * SLOTS + c] = v;
    } else {
        atomicAdd(&degx[s], ww);
        int o = atomicAdd(ovf_cnt, 1);
        if (o < OVF_CAP) { ovf[o * 3] = s; ovf[o * 3 + 1] = d; ovf[o * 3 + 2] = __float_as_int(ww); }
    }
}

// one 64-lane wave per node
__global__ __launch_bounds__(256) void k_agg(
    const int* __restrict__ cursor, const uint2* __restrict__ slots,
    const float* __restrict__ degx, float* __restrict__ inv_arr,
    const float2* __restrict__ x2, float2* __restrict__ out2) {
    int wid  = (int)((blockIdx.x * (long long)blockDim.x + threadIdx.x) >> 6);
    int lane = threadIdx.x & 63;
    if (wid >= N_NODES) return;

    int c = min(cursor[wid], SLOTS);

    int   dv = 0;
    float wv = 0.0f;
    if (lane < c) {
        uint2 sl = slots[(size_t)wid * SLOTS + lane];   // coalesced 512B/wave
        dv = (int)sl.x;
        wv = __uint_as_float(sl.y);
    }

    // wave-reduce sum of weights -> degree
    float wsum = wv;
    #pragma unroll
    for (int off = 1; off < 64; off <<= 1) wsum += __shfl_xor(wsum, off);
    float deg = 1.0f + wsum + degx[wid];
    float inv = 1.0f / fmaxf(deg, 1.0f);
    if (lane == 0) inv_arr[wid] = inv;

    float2 acc = x2[(size_t)wid * 64 + lane];   // self-loop, weight 1

    int k = 0;
    for (; k + 3 < c; k += 4) {
        int   d0 = __shfl(dv, k),     d1 = __shfl(dv, k + 1);
        int   d2 = __shfl(dv, k + 2), d3 = __shfl(dv, k + 3);
        float w0 = __shfl(wv, k),     w1 = __shfl(wv, k + 1);
        float w2 = __shfl(wv, k + 2), w3 = __shfl(wv, k + 3);
        float2 v0 = x2[(size_t)d0 * 64 + lane];
        float2 v1 = x2[(size_t)d1 * 64 + lane];
        float2 v2 = x2[(size_t)d2 * 64 + lane];
        float2 v3 = x2[(size_t)d3 * 64 + lane];
        acc.x += w0 * v0.x + w1 * v1.x + w2 * v2.x + w3 * v3.x;
        acc.y += w0 * v0.y + w1 * v1.y + w2 * v2.y + w3 * v3.y;
    }
    for (; k < c; ++k) {
        int   d = __shfl(dv, k);
        float w = __shfl(wv, k);
        float2 v = x2[(size_t)d * 64 + lane];
        acc.x += w * v.x;
        acc.y += w * v.y;
    }
    out2[(size_t)wid * 64 + lane] = make_float2(acc.x * inv, acc.y * inv);
}

// overflow fixup (n == 0 in practice; exits immediately)
__global__ void k_ovf(const int* __restrict__ ovf_cnt, const int* __restrict__ ovf,
                      const float* __restrict__ inv_arr,
                      const float* __restrict__ x, float* __restrict__ out) {
    int n = min(*ovf_cnt, OVF_CAP);
    for (int i = blockIdx.x * blockDim.x + threadIdx.x; i < n;
         i += gridDim.x * blockDim.x) {
        int s = ovf[i * 3], d = ovf[i * 3 + 1];
        float sc = __int_as_float(ovf[i * 3 + 2]) * inv_arr[s];
        for (int f = 0; f < N_FEAT; ++f)
            atomicAdd(&out[(size_t)s * N_FEAT + f], sc * x[(size_t)d * N_FEAT + f]);
    }
}

// ---------------- CSR fallback (round-2 path, ~14.4 MB ws) ----------------
constexpr size_t F_CNT = 0;
constexpr size_t F_ROW = F_CNT + align_up(N_NODES * 4);
constexpr size_t F_CUR = F_ROW + align_up(N_NODES * 4);
constexpr size_t F_DEG = F_CUR + align_up(N_NODES * 4);
constexpr size_t F_TOT = F_DEG + align_up(N_NODES * 4);
constexpr size_t F_DST = F_TOT + 256;
constexpr size_t F_W   = F_DST + align_up(N_EDGES * 4);
constexpr size_t WS_CSR = F_W + N_EDGES * 4;

__global__ void c_init(int* cnt, float* deg, int* total) {
    int i = blockIdx.x * blockDim.x + threadIdx.x;
    if (i < N_NODES) { cnt[i] = 0; deg[i] = 1.0f; }
    if (i == 0) *total = 0;
}
__global__ void c_count(const int* src, const float* w, int* cnt, float* deg) {
    int e = blockIdx.x * blockDim.x + threadIdx.x;
    if (e < N_EDGES) { int s = src[e]; atomicAdd(&cnt[s], 1); atomicAdd(&deg[s], w[e]); }
}
__global__ void c_alloc(const int* cnt, int* rowstart, int* cursor, float* deg, int* total) {
    int i = blockIdx.x * blockDim.x + threadIdx.x;
    if (i < N_NODES) {
        int c = cnt[i]; int s = atomicAdd(total, c);
        rowstart[i] = s; cursor[i] = s;
        deg[i] = 1.0f / fmaxf(deg[i], 1.0f);
    }
}
__global__ void c_scatter(const int* src, const int* dst, const float* w,
                          int* cursor, int* csr_dst, float* csr_w) {
    int e = blockIdx.x * blockDim.x + threadIdx.x;
    if (e < N_EDGES) {
        int pos = atomicAdd(&cursor[src[e]], 1);
        csr_dst[pos] = dst[e]; csr_w[pos] = w[e];
    }
}
__global__ __launch_bounds__(256) void c_agg(
    const int* rowstart, const int* cnt, const float* inv,
    const int* csr_dst, const float* csr_w,
    const float2* x2, float2* out2) {
    int wid  = (int)((blockIdx.x * (long long)blockDim.x + threadIdx.x) >> 6);
    int lane = threadIdx.x & 63;
    if (wid >= N_NODES) return;
    int s = rowstart[wid], c = cnt[wid];
    float2 acc = x2[(size_t)wid * 64 + lane];
    for (int base = 0; base < c; base += 64) {
        int dv = 0; float wv = 0.0f;
        int idx = base + lane;
        if (idx < c) { dv = csr_dst[s + idx]; wv = csr_w[s + idx]; }
        int m = min(64, c - base);
        for (int k = 0; k < m; ++k) {
            int d = __shfl(dv, k); float w = __shfl(wv, k);
            float2 v = x2[(size_t)d * 64 + lane];
            acc.x += w * v.x; acc.y += w * v.y;
        }
    }
    float si = inv[wid];
    out2[(size_t)wid * 64 + lane] = make_float2(acc.x * si, acc.y * si);
}

// ---------------- atomic fallback (round-1 path) ----------------
__global__ void fb_init_deg(float* deg) {
    int i = blockIdx.x * blockDim.x + threadIdx.x;
    if (i < N_NODES) deg[i] = 1.0f;
}
__global__ void fb_accum_deg(const int* src, const float* w, float* deg) {
    int e = blockIdx.x * blockDim.x + threadIdx.x;
    if (e < N_EDGES) atomicAdd(&deg[src[e]], w[e]);
}
__global__ void fb_inv_deg(float* deg) {
    int i = blockIdx.x * blockDim.x + threadIdx.x;
    if (i < N_NODES) deg[i] = 1.0f / fmaxf(deg[i], 1.0f);
}
__global__ void fb_self(const float4* x4, const float* inv, float4* out4) {
    int idx = blockIdx.x * blockDim.x + threadIdx.x;
    if (idx < N_NODES * (N_FEAT / 4)) {
        int node = idx >> 5; float s = inv[node];
        float4 v = x4[idx];
        out4[idx] = make_float4(v.x * s, v.y * s, v.z * s, v.w * s);
    }
}
__global__ void fb_edges(const int* src, const int* dst, const float* w,
                         const float* inv, const float4* x4, float* out) {
    long long gid = (long long)blockIdx.x * blockDim.x + threadIdx.x;
    int e = (int)(gid >> 5); int lane = (int)(gid & 31);
    if (e < N_EDGES) {
        int s = src[e];
        float sc = w[e] * inv[s];
        float4 v = x4[(long long)dst[e] * (N_FEAT / 4) + lane];
        float* ob = out + (long long)s * N_FEAT + lane * 4;
        atomicAdd(ob + 0, sc * v.x); atomicAdd(ob + 1, sc * v.y);
        atomicAdd(ob + 2, sc * v.z); atomicAdd(ob + 3, sc * v.w);
    }
}

extern "C" void kernel_launch(void* const* d_in, const int* in_sizes, int n_in,
                              void* d_out, int out_size, void* d_ws, size_t ws_size,
                              hipStream_t stream) {
    const float* x          = (const float*)d_in[0];
    const int*   edge_index = (const int*)d_in[1];   // (2, E) row-major
    const float* edge_w     = (const float*)d_in[2];
    const int* src = edge_index;
    const int* dst = edge_index + N_EDGES;
    float* out = (float*)d_out;
    const int B = 256;

    if (ws_size >= WS_FAST) {
        char* ws = (char*)d_ws;
        int*   cursor  = (int*)  (ws + OFF_CUR);
        float* degx    = (float*)(ws + OFF_DEGX);
        int*   ovf_cnt = (int*)  (ws + OFF_OVFC);
        float* inv_arr = (float*)(ws + OFF_INV);
        int*   ovf     = (int*)  (ws + OFF_OVF);
        uint2* slots   = (uint2*)(ws + OFF_SLOT);

        hipMemsetAsync(d_ws, 0, ZERO_LEN, stream);
        k_build<<<(N_EDGES + B - 1) / B, B, 0, stream>>>(
            src, dst, edge_w, cursor, slots, degx, ovf_cnt, ovf);
        long long threads = (long long)N_NODES * 64;
        k_agg<<<(int)((threads + B - 1) / B), B, 0, stream>>>(
            cursor, slots, degx, inv_arr, (const float2*)x, (float2*)out);
        k_ovf<<<32, 256, 0, stream>>>(ovf_cnt, ovf, inv_arr, x, out);
        return;
    }

    if (ws_size >= WS_CSR) {
        char* ws = (char*)d_ws;
        int*   cnt      = (int*)  (ws + F_CNT);
        int*   rowstart = (int*)  (ws + F_ROW);
        int*   cursor   = (int*)  (ws + F_CUR);
        float* deg      = (float*)(ws + F_DEG);
        int*   total    = (int*)  (ws + F_TOT);
        int*   csr_dst  = (int*)  (ws + F_DST);
        float* csr_w    = (float*)(ws + F_W);
        c_init<<<(N_NODES + B - 1) / B, B, 0, stream>>>(cnt, deg, total);
        c_count<<<(N_EDGES + B - 1) / B, B, 0, stream>>>(src, edge_w, cnt, deg);
        c_alloc<<<(N_NODES + B - 1) / B, B, 0, stream>>>(cnt, rowstart, cursor, deg, total);
        c_scatter<<<(N_EDGES + B - 1) / B, B, 0, stream>>>(src, dst, edge_w, cursor,
                                                           csr_dst, csr_w);
        long long threads = (long long)N_NODES * 64;
        c_agg<<<(int)((threads + B - 1) / B), B, 0, stream>>>(
            rowstart, cnt, deg, csr_dst, csr_w, (const float2*)x, (float2*)out);
        return;
    }

    // minimal-ws fallback
    float* deg = (float*)d_ws;
    fb_init_deg<<<(N_NODES + B - 1) / B, B, 0, stream>>>(deg);
    fb_accum_deg<<<(N_EDGES + B - 1) / B, B, 0, stream>>>(src, edge_w, deg);
    fb_inv_deg<<<(N_NODES + B - 1) / B, B, 0, stream>>>(deg);
    int n4 = N_NODES * (N_FEAT / 4);
    fb_self<<<(n4 + B - 1) / B, B, 0, stream>>>((const float4*)x, deg, (float4*)out);
    long long total = (long long)N_EDGES * 32;
    fb_edges<<<(int)((total + B - 1) / B), B, 0, stream>>>(
        src, dst, edge_w, deg, (const float4*)x, out);
}

// Round 4
// 220.454 us; speedup vs baseline: 12.6159x; 1.1112x over previous
//
#include <hip/hip_runtime.h>
#include <hip/hip_fp16.h>

#define N_NODES 100000
#define N_FEAT  128
#define N_EDGES 1600000
#define OVF_CAP 65536

constexpr size_t align_up(size_t x) { return (x + 255) & ~size_t(255); }

// ================= tier 1: fp16-gather fast path (SLOTS=48) =================
#define SLOTS_H 48
constexpr size_t H_CUR  = 0;                                    // N ints (zeroed)
constexpr size_t H_DEGX = H_CUR  + align_up(N_NODES * 4);       // N floats (zeroed)
constexpr size_t H_OVFC = H_DEGX + align_up(N_NODES * 4);       // 1 int (zeroed)
constexpr size_t H_INV  = H_OVFC + 256;                         // N floats
constexpr size_t H_OVF  = H_INV  + align_up(N_NODES * 4);       // OVF_CAP*12
constexpr size_t H_XH   = H_OVF  + align_up(OVF_CAP * 12);      // N*64 uint (fp16 x)
constexpr size_t H_SLOT = H_XH   + align_up((size_t)N_NODES * 64 * 4); // N*SLOTS_H uint2
constexpr size_t WS_H   = H_SLOT + (size_t)N_NODES * SLOTS_H * 8;     // ~66 MB
constexpr size_t H_ZERO = H_OVFC + 256;

#define NCONV (N_NODES * N_FEAT / 4)   // 3.2M float4s

// fused: x fp32 -> fp16 conversion (streaming) + edge binning (atomic-bound)
__global__ void k_build_conv(const int* __restrict__ src, const int* __restrict__ dst,
                             const float* __restrict__ w,
                             const float4* __restrict__ x4, uint2* __restrict__ xh_u2,
                             int* __restrict__ cursor, uint2* __restrict__ slots,
                             float* __restrict__ degx,
                             int* __restrict__ ovf_cnt, int* __restrict__ ovf) {
    int gid = blockIdx.x * blockDim.x + threadIdx.x;
    if (gid < NCONV) {
        float4 v = x4[gid];
        __half2 h0 = __floats2half2_rn(v.x, v.y);
        __half2 h1 = __floats2half2_rn(v.z, v.w);
        uint2 u;
        __builtin_memcpy(&u.x, &h0, 4);
        __builtin_memcpy(&u.y, &h1, 4);
        xh_u2[gid] = u;
        return;
    }
    int e = gid - NCONV;
    if (e >= N_EDGES) return;
    int   s  = src[e];
    int   d  = dst[e];
    float ww = w[e];
    int c = atomicAdd(&cursor[s], 1);
    if (c < SLOTS_H) {
        uint2 v;
        v.x = (unsigned)d;
        v.y = __float_as_uint(ww);
        slots[(size_t)s * SLOTS_H + c] = v;
    } else {
        atomicAdd(&degx[s], ww);
        int o = atomicAdd(ovf_cnt, 1);
        if (o < OVF_CAP) { ovf[o*3] = s; ovf[o*3+1] = d; ovf[o*3+2] = __float_as_int(ww); }
    }
}

// one 64-lane wave per node; gathers fp16 rows (256 B/row), fp32 accumulate
__global__ __launch_bounds__(256) void k_agg_h(
    const int* __restrict__ cursor, const uint2* __restrict__ slots,
    const float* __restrict__ degx, float* __restrict__ inv_arr,
    const unsigned* __restrict__ xh_u, float2* __restrict__ out2) {
    int wid  = (int)((blockIdx.x * (long long)blockDim.x + threadIdx.x) >> 6);
    int lane = threadIdx.x & 63;
    if (wid >= N_NODES) return;

    int c = min(cursor[wid], SLOTS_H);

    int   dv = 0;
    float wv = 0.0f;
    if (lane < c) {
        uint2 sl = slots[(size_t)wid * SLOTS_H + lane];
        dv = (int)sl.x;
        wv = __uint_as_float(sl.y);
    }

    float wsum = wv;
    #pragma unroll
    for (int off = 1; off < 64; off <<= 1) wsum += __shfl_xor(wsum, off);
    float deg = 1.0f + wsum + degx[wid];
    float inv = 1.0f / fmaxf(deg, 1.0f);
    if (lane == 0) inv_arr[wid] = inv;

    // self-loop (weight 1), fp16 row
    unsigned us = xh_u[(size_t)wid * 64 + lane];
    __half2 hs; __builtin_memcpy(&hs, &us, 4);
    float2 acc = __half22float2(hs);

    int k = 0;
    for (; k + 7 < c; k += 8) {
        float2 vv[8]; float ww[8];
        #pragma unroll
        for (int j = 0; j < 8; ++j) {
            int   d = __shfl(dv, k + j);
            ww[j]   = __shfl(wv, k + j);
            unsigned u = xh_u[(size_t)d * 64 + lane];
            __half2 h; __builtin_memcpy(&h, &u, 4);
            vv[j] = __half22float2(h);
        }
        #pragma unroll
        for (int j = 0; j < 8; ++j) { acc.x += ww[j] * vv[j].x; acc.y += ww[j] * vv[j].y; }
    }
    for (; k < c; ++k) {
        int   d = __shfl(dv, k);
        float w = __shfl(wv, k);
        unsigned u = xh_u[(size_t)d * 64 + lane];
        __half2 h; __builtin_memcpy(&h, &u, 4);
        float2 v = __half22float2(h);
        acc.x += w * v.x; acc.y += w * v.y;
    }
    out2[(size_t)wid * 64 + lane] = make_float2(acc.x * inv, acc.y * inv);
}

__global__ void k_ovf(const int* __restrict__ ovf_cnt, const int* __restrict__ ovf,
                      const float* __restrict__ inv_arr,
                      const float* __restrict__ x, float* __restrict__ out) {
    int n = min(*ovf_cnt, OVF_CAP);
    for (int i = blockIdx.x * blockDim.x + threadIdx.x; i < n;
         i += gridDim.x * blockDim.x) {
        int s = ovf[i*3], d = ovf[i*3+1];
        float sc = __int_as_float(ovf[i*3+2]) * inv_arr[s];
        for (int f = 0; f < N_FEAT; ++f)
            atomicAdd(&out[(size_t)s * N_FEAT + f], sc * x[(size_t)d * N_FEAT + f]);
    }
}

// ================= tier 2: fp32 slot path (round-3, SLOTS=64, ~53.2 MB) =====
#define SLOTS_F 64
constexpr size_t G_CUR  = 0;
constexpr size_t G_DEGX = G_CUR  + align_up(N_NODES * 4);
constexpr size_t G_OVFC = G_DEGX + align_up(N_NODES * 4);
constexpr size_t G_INV  = G_OVFC + 256;
constexpr size_t G_OVF  = G_INV  + align_up(N_NODES * 4);
constexpr size_t G_SLOT = G_OVF  + align_up(OVF_CAP * 12);
constexpr size_t WS_G   = G_SLOT + (size_t)N_NODES * SLOTS_F * 8;
constexpr size_t G_ZERO = G_OVFC + 256;

__global__ void g_build(const int* __restrict__ src, const int* __restrict__ dst,
                        const float* __restrict__ w,
                        int* __restrict__ cursor, uint2* __restrict__ slots,
                        float* __restrict__ degx,
                        int* __restrict__ ovf_cnt, int* __restrict__ ovf) {
    int e = blockIdx.x * blockDim.x + threadIdx.x;
    if (e >= N_EDGES) return;
    int s = src[e], d = dst[e];
    float ww = w[e];
    int c = atomicAdd(&cursor[s], 1);
    if (c < SLOTS_F) {
        uint2 v; v.x = (unsigned)d; v.y = __float_as_uint(ww);
        slots[(size_t)s * SLOTS_F + c] = v;
    } else {
        atomicAdd(&degx[s], ww);
        int o = atomicAdd(ovf_cnt, 1);
        if (o < OVF_CAP) { ovf[o*3] = s; ovf[o*3+1] = d; ovf[o*3+2] = __float_as_int(ww); }
    }
}

__global__ __launch_bounds__(256) void g_agg(
    const int* __restrict__ cursor, const uint2* __restrict__ slots,
    const float* __restrict__ degx, float* __restrict__ inv_arr,
    const float2* __restrict__ x2, float2* __restrict__ out2) {
    int wid  = (int)((blockIdx.x * (long long)blockDim.x + threadIdx.x) >> 6);
    int lane = threadIdx.x & 63;
    if (wid >= N_NODES) return;
    int c = min(cursor[wid], SLOTS_F);
    int dv = 0; float wv = 0.0f;
    if (lane < c) {
        uint2 sl = slots[(size_t)wid * SLOTS_F + lane];
        dv = (int)sl.x; wv = __uint_as_float(sl.y);
    }
    float wsum = wv;
    #pragma unroll
    for (int off = 1; off < 64; off <<= 1) wsum += __shfl_xor(wsum, off);
    float deg = 1.0f + wsum + degx[wid];
    float inv = 1.0f / fmaxf(deg, 1.0f);
    if (lane == 0) inv_arr[wid] = inv;
    float2 acc = x2[(size_t)wid * 64 + lane];
    int k = 0;
    for (; k + 3 < c; k += 4) {
        int   d0 = __shfl(dv, k),   d1 = __shfl(dv, k+1);
        int   d2 = __shfl(dv, k+2), d3 = __shfl(dv, k+3);
        float w0 = __shfl(wv, k),   w1 = __shfl(wv, k+1);
        float w2 = __shfl(wv, k+2), w3 = __shfl(wv, k+3);
        float2 v0 = x2[(size_t)d0 * 64 + lane];
        float2 v1 = x2[(size_t)d1 * 64 + lane];
        float2 v2 = x2[(size_t)d2 * 64 + lane];
        float2 v3 = x2[(size_t)d3 * 64 + lane];
        acc.x += w0*v0.x + w1*v1.x + w2*v2.x + w3*v3.x;
        acc.y += w0*v0.y + w1*v1.y + w2*v2.y + w3*v3.y;
    }
    for (; k < c; ++k) {
        int d = __shfl(dv, k); float w = __shfl(wv, k);
        float2 v = x2[(size_t)d * 64 + lane];
        acc.x += w * v.x; acc.y += w * v.y;
    }
    out2[(size_t)wid * 64 + lane] = make_float2(acc.x * inv, acc.y * inv);
}

// ================= tier 3: CSR path (~14.4 MB) =================
constexpr size_t F_CNT = 0;
constexpr size_t F_ROW = F_CNT + align_up(N_NODES * 4);
constexpr size_t F_CUR = F_ROW + align_up(N_NODES * 4);
constexpr size_t F_DEG = F_CUR + align_up(N_NODES * 4);
constexpr size_t F_TOT = F_DEG + align_up(N_NODES * 4);
constexpr size_t F_DST = F_TOT + 256;
constexpr size_t F_W   = F_DST + align_up(N_EDGES * 4);
constexpr size_t WS_CSR = F_W + N_EDGES * 4;

__global__ void c_init(int* cnt, float* deg, int* total) {
    int i = blockIdx.x * blockDim.x + threadIdx.x;
    if (i < N_NODES) { cnt[i] = 0; deg[i] = 1.0f; }
    if (i == 0) *total = 0;
}
__global__ void c_count(const int* src, const float* w, int* cnt, float* deg) {
    int e = blockIdx.x * blockDim.x + threadIdx.x;
    if (e < N_EDGES) { int s = src[e]; atomicAdd(&cnt[s], 1); atomicAdd(&deg[s], w[e]); }
}
__global__ void c_alloc(const int* cnt, int* rowstart, int* cursor, float* deg, int* total) {
    int i = blockIdx.x * blockDim.x + threadIdx.x;
    if (i < N_NODES) {
        int c = cnt[i]; int s = atomicAdd(total, c);
        rowstart[i] = s; cursor[i] = s;
        deg[i] = 1.0f / fmaxf(deg[i], 1.0f);
    }
}
__global__ void c_scatter(const int* src, const int* dst, const float* w,
                          int* cursor, int* csr_dst, float* csr_w) {
    int e = blockIdx.x * blockDim.x + threadIdx.x;
    if (e < N_EDGES) {
        int pos = atomicAdd(&cursor[src[e]], 1);
        csr_dst[pos] = dst[e]; csr_w[pos] = w[e];
    }
}
__global__ __launch_bounds__(256) void c_agg(
    const int* rowstart, const int* cnt, const float* inv,
    const int* csr_dst, const float* csr_w,
    const float2* x2, float2* out2) {
    int wid  = (int)((blockIdx.x * (long long)blockDim.x + threadIdx.x) >> 6);
    int lane = threadIdx.x & 63;
    if (wid >= N_NODES) return;
    int s = rowstart[wid], c = cnt[wid];
    float2 acc = x2[(size_t)wid * 64 + lane];
    for (int base = 0; base < c; base += 64) {
        int dv = 0; float wv = 0.0f;
        int idx = base + lane;
        if (idx < c) { dv = csr_dst[s + idx]; wv = csr_w[s + idx]; }
        int m = min(64, c - base);
        for (int k = 0; k < m; ++k) {
            int d = __shfl(dv, k); float w = __shfl(wv, k);
            float2 v = x2[(size_t)d * 64 + lane];
            acc.x += w * v.x; acc.y += w * v.y;
        }
    }
    float si = inv[wid];
    out2[(size_t)wid * 64 + lane] = make_float2(acc.x * si, acc.y * si);
}

// ================= tier 4: atomic fallback =================
__global__ void fb_init_deg(float* deg) {
    int i = blockIdx.x * blockDim.x + threadIdx.x;
    if (i < N_NODES) deg[i] = 1.0f;
}
__global__ void fb_accum_deg(const int* src, const float* w, float* deg) {
    int e = blockIdx.x * blockDim.x + threadIdx.x;
    if (e < N_EDGES) atomicAdd(&deg[src[e]], w[e]);
}
__global__ void fb_inv_deg(float* deg) {
    int i = blockIdx.x * blockDim.x + threadIdx.x;
    if (i < N_NODES) deg[i] = 1.0f / fmaxf(deg[i], 1.0f);
}
__global__ void fb_self(const float4* x4, const float* inv, float4* out4) {
    int idx = blockIdx.x * blockDim.x + threadIdx.x;
    if (idx < N_NODES * (N_FEAT / 4)) {
        int node = idx >> 5; float s = inv[node];
        float4 v = x4[idx];
        out4[idx] = make_float4(v.x*s, v.y*s, v.z*s, v.w*s);
    }
}
__global__ void fb_edges(const int* src, const int* dst, const float* w,
                         const float* inv, const float4* x4, float* out) {
    long long gid = (long long)blockIdx.x * blockDim.x + threadIdx.x;
    int e = (int)(gid >> 5); int lane = (int)(gid & 31);
    if (e < N_EDGES) {
        int s = src[e];
        float sc = w[e] * inv[s];
        float4 v = x4[(long long)dst[e] * (N_FEAT/4) + lane];
        float* ob = out + (long long)s * N_FEAT + lane * 4;
        atomicAdd(ob+0, sc*v.x); atomicAdd(ob+1, sc*v.y);
        atomicAdd(ob+2, sc*v.z); atomicAdd(ob+3, sc*v.w);
    }
}

extern "C" void kernel_launch(void* const* d_in, const int* in_sizes, int n_in,
                              void* d_out, int out_size, void* d_ws, size_t ws_size,
                              hipStream_t stream) {
    const float* x          = (const float*)d_in[0];
    const int*   edge_index = (const int*)d_in[1];   // (2, E) row-major
    const float* edge_w     = (const float*)d_in[2];
    const int* src = edge_index;
    const int* dst = edge_index + N_EDGES;
    float* out = (float*)d_out;
    const int B = 256;

    if (ws_size >= WS_H) {
        char* ws = (char*)d_ws;
        int*      cursor  = (int*)     (ws + H_CUR);
        float*    degx    = (float*)   (ws + H_DEGX);
        int*      ovf_cnt = (int*)     (ws + H_OVFC);
        float*    inv_arr = (float*)   (ws + H_INV);
        int*      ovf     = (int*)     (ws + H_OVF);
        uint2*    xh_u2   = (uint2*)   (ws + H_XH);
        unsigned* xh_u    = (unsigned*)(ws + H_XH);
        uint2*    slots   = (uint2*)   (ws + H_SLOT);

        hipMemsetAsync(d_ws, 0, H_ZERO, stream);
        long long t_build = (long long)NCONV + N_EDGES;
        k_build_conv<<<(int)((t_build + B - 1) / B), B, 0, stream>>>(
            src, dst, edge_w, (const float4*)x, xh_u2,
            cursor, slots, degx, ovf_cnt, ovf);
        long long t_agg = (long long)N_NODES * 64;
        k_agg_h<<<(int)((t_agg + B - 1) / B), B, 0, stream>>>(
            cursor, slots, degx, inv_arr, xh_u, (float2*)out);
        k_ovf<<<32, 256, 0, stream>>>(ovf_cnt, ovf, inv_arr, x, out);
        return;
    }

    if (ws_size >= WS_G) {
        char* ws = (char*)d_ws;
        int*   cursor  = (int*)  (ws + G_CUR);
        float* degx    = (float*)(ws + G_DEGX);
        int*   ovf_cnt = (int*)  (ws + G_OVFC);
        float* inv_arr = (float*)(ws + G_INV);
        int*   ovf     = (int*)  (ws + G_OVF);
        uint2* slots   = (uint2*)(ws + G_SLOT);
        hipMemsetAsync(d_ws, 0, G_ZERO, stream);
        g_build<<<(N_EDGES + B - 1) / B, B, 0, stream>>>(
            src, dst, edge_w, cursor, slots, degx, ovf_cnt, ovf);
        long long t_agg = (long long)N_NODES * 64;
        g_agg<<<(int)((t_agg + B - 1) / B), B, 0, stream>>>(
            cursor, slots, degx, inv_arr, (const float2*)x, (float2*)out);
        k_ovf<<<32, 256, 0, stream>>>(ovf_cnt, ovf, inv_arr, x, out);
        return;
    }

    if (ws_size >= WS_CSR) {
        char* ws = (char*)d_ws;
        int*   cnt      = (int*)  (ws + F_CNT);
        int*   rowstart = (int*)  (ws + F_ROW);
        int*   cursor   = (int*)  (ws + F_CUR);
        float* deg      = (float*)(ws + F_DEG);
        int*   total    = (int*)  (ws + F_TOT);
        int*   csr_dst  = (int*)  (ws + F_DST);
        float* csr_w    = (float*)(ws + F_W);
        c_init<<<(N_NODES + B - 1) / B, B, 0, stream>>>(cnt, deg, total);
        c_count<<<(N_EDGES + B - 1) / B, B, 0, stream>>>(src, edge_w, cnt, deg);
        c_alloc<<<(N_NODES + B - 1) / B, B, 0, stream>>>(cnt, rowstart, cursor, deg, total);
        c_scatter<<<(N_EDGES + B - 1) / B, B, 0, stream>>>(src, dst, edge_w, cursor,
                                                           csr_dst, csr_w);
        long long t_agg = (long long)N_NODES * 64;
        c_agg<<<(int)((t_agg + B - 1) / B), B, 0, stream>>>(
            rowstart, cnt, deg, csr_dst, csr_w, (const float2*)x, (float2*)out);
        return;
    }

    float* deg = (float*)d_ws;
    fb_init_deg<<<(N_NODES + B - 1) / B, B, 0, stream>>>(deg);
    fb_accum_deg<<<(N_EDGES + B - 1) / B, B, 0, stream>>>(src, edge_w, deg);
    fb_inv_deg<<<(N_NODES + B - 1) / B, B, 0, stream>>>(deg);
    int n4 = N_NODES * (N_FEAT / 4);
    fb_self<<<(n4 + B - 1) / B, B, 0, stream>>>((const float4*)x, deg, (float4*)out);
    long long total = (long long)N_EDGES * 32;
    fb_edges<<<(int)((total + B - 1) / B), B, 0, stream>>>(
        src, dst, edge_w, deg, (const float4*)x, out);
}